// Round 5
// baseline (3946.989 us; speedup 1.0000x reference)
//
#include <hip/hip_runtime.h>
#include <hip/hip_bf16.h>

// Problem dims
#define BB   32      // batch
#define NN   98      // image regions
#define EE   2048    // img feature dim
#define HH   512     // hidden
#define VV   10000   // vocab
#define TT   60      // timesteps (T_CAP-1)
#define TCAP 61
#define NBLK 512     // persistent-loop grid (2 blocks per CU; co-resident)
#define FLAGOFF 512  // u32 offset of broadcast flag lines in sync area

typedef unsigned short u16;
typedef unsigned long long u64;
typedef __attribute__((ext_vector_type(8))) short bh8;
typedef __attribute__((ext_vector_type(4))) float f32x4;

__device__ __forceinline__ float bsf(unsigned s) {
    union { unsigned u; float f; } w; w.u = s << 16; return w.f;
}
__device__ __forceinline__ u16 f2bu(float f) {
    union { float f; unsigned u; } v; v.f = f;
    unsigned u = v.u;
    u = u + 0x7fffu + ((u >> 16) & 1u);   // RNE
    return (u16)(u >> 16);
}
__device__ __forceinline__ bh8 ld8(const u16* p) {
    return *reinterpret_cast<const bh8*>(p);
}
__device__ __forceinline__ float sigm(float x) {
    return __builtin_amdgcn_rcpf(1.0f + exp2f(-1.4426950408889634f * x));
}
__device__ __forceinline__ float tanh_(float x) {
    return 1.0f - 2.0f * __builtin_amdgcn_rcpf(1.0f + exp2f(2.885390081777927f * x));
}

// ---- agent-coherent (cache-bypassing, sc0+sc1) accessors for cross-block data.
__device__ __forceinline__ u64 ldu64_coh(const void* p) {
    return __hip_atomic_load((const u64*)p, __ATOMIC_RELAXED, __HIP_MEMORY_SCOPE_AGENT);
}
__device__ __forceinline__ bh8 ld8_coh(const u16* p) {
    union { u64 u[2]; bh8 v; } w;
    w.u[0] = ldu64_coh(p); w.u[1] = ldu64_coh(p + 4);
    return w.v;
}
__device__ __forceinline__ float2 ldf2_coh(const float* p) {
    union { u64 u; float2 f; } w; w.u = ldu64_coh(p); return w.f;
}
__device__ __forceinline__ void stf_coh(float* p, float v) {
    __hip_atomic_store(p, v, __ATOMIC_RELAXED, __HIP_MEMORY_SCOPE_AGENT);
}
__device__ __forceinline__ void stu16_coh(u16* p, u16 v) {
    __hip_atomic_store(p, v, __ATOMIC_RELAXED, __HIP_MEMORY_SCOPE_AGENT);
}
__device__ __forceinline__ void stu32_coh(unsigned* p, unsigned v) {
    __hip_atomic_store(p, v, __ATOMIC_RELAXED, __HIP_MEMORY_SCOPE_AGENT);
}
__device__ __forceinline__ unsigned ldu32_coh(const unsigned* p) {
    return __hip_atomic_load(p, __ATOMIC_RELAXED, __HIP_MEMORY_SCOPE_AGENT);
}

// ---------------- k_conv_all: all 9 fp32->bf16 conversions in one launch ------
// dst regions are contiguous in ws: [img|Watt|Winh|Winc|WU|Wfb|Wih|Whh|Wout].
__global__ __launch_bounds__(256) void k_conv_all(
    const float* __restrict__ s_img, const float* __restrict__ s_watt,
    const float* __restrict__ s_winh, const float* __restrict__ s_winc,
    const float* __restrict__ s_wu,  const float* __restrict__ s_wfb,
    const float* __restrict__ s_wih, const float* __restrict__ s_whh,
    const float* __restrict__ s_wout, u16* __restrict__ dst)
{
    size_t i = (size_t)blockIdx.x * 256 + threadIdx.x;   // float4 index
    size_t e = i * 4;                                     // element index
    const float* src; size_t off;
    if      (e <  6422528) { src = s_img;  off = 0; }
    else if (e <  7471104) { src = s_watt; off = 6422528; }
    else if (e <  8519680) { src = s_winh; off = 7471104; }
    else if (e <  9568256) { src = s_winc; off = 8519680; }
    else if (e <  9830400) { src = s_wu;   off = 9568256; }
    else if (e < 10878976) { src = s_wfb;  off = 9830400; }
    else if (e < 16121856) { src = s_wih;  off = 10878976; }
    else if (e < 17170432) { src = s_whh;  off = 16121856; }
    else                   { src = s_wout; off = 17170432; }
    float4 v = reinterpret_cast<const float4*>(src)[(e - off) >> 2];
    ushort4 o;
    o.x = f2bu(v.x); o.y = f2bu(v.y); o.z = f2bu(v.z); o.w = f2bu(v.w);
    reinterpret_cast<ushort4*>(dst)[i] = o;
}

// ---------------- init1: avg features (fp32) + scaled embedding gather --------
__global__ __launch_bounds__(256) void k_init1(
    const float* __restrict__ img, const int* __restrict__ caps,
    const float* __restrict__ emb, u16* __restrict__ avg_bf, u16* __restrict__ emb_all)
{
    int bid = blockIdx.x, tid = threadIdx.x;
    if (bid < 256) {
        int b = bid >> 3, et = bid & 7;
        int ec = et * 256 + tid;
        const float* p = img + (size_t)(b * NN) * EE + ec;
        float s = 0.f;
        for (int n = 0; n < NN; ++n) s += p[(size_t)n * EE];
        avg_bf[b * EE + ec] = f2bu(s * (1.0f / 98.0f));
    } else {
        int eb = bid - 256;                  // 240 blocks x 8 rows = 1920 rows
        for (int r8 = 0; r8 < 8; ++r8) {
            int row = eb * 8 + r8;           // row = t*32 + b
            int t = row >> 5, b = row & 31;
            int cap = caps[b * TCAP + t];
            const float* src = emb + (size_t)cap * HH;
            u16* dst = emb_all + (size_t)row * HH;
            for (int c = tid; c < HH; c += 256)
                dst[c] = f2bu(src[c] * 22.627416997969522f);  // sqrt(512)
        }
    }
}

// ---------------- init2: h0 = tanh(avg@W_init_h.T+b), c0 likewise (MFMA) ------
__global__ __launch_bounds__(256) void k_init2(
    const u16* __restrict__ avg_bf,
    const u16* __restrict__ Wh_bf, const float* __restrict__ b_h,
    const u16* __restrict__ Wc_bf, const float* __restrict__ b_c,
    u16* __restrict__ h_all, float* __restrict__ c_ws)
{
    __shared__ float red[4][2][64][4];
    int ot = blockIdx.x, tid = threadIdx.x;       // 64 blocks x 16 outputs (1024 total)
    int w = tid >> 6, lane = tid & 63, quad = lane >> 4, l16 = lane & 15;
    int o = ot * 16 + l16;
    const u16* wrow = (o < HH) ? (Wh_bf + (size_t)o * EE) : (Wc_bf + (size_t)(o - HH) * EE);
    f32x4 acc[2]; acc[0] = {0,0,0,0}; acc[1] = {0,0,0,0};
    for (int c = w * 16; c < w * 16 + 16; ++c) {
        int k = c * 32 + quad * 8;
        bh8 b8 = ld8(wrow + k);
        for (int mt = 0; mt < 2; ++mt) {
            bh8 a8 = ld8(avg_bf + (size_t)(mt * 16 + l16) * EE + k);
            acc[mt] = __builtin_amdgcn_mfma_f32_16x16x32_bf16(a8, b8, acc[mt], 0, 0, 0);
        }
    }
    for (int mt = 0; mt < 2; ++mt)
        for (int r = 0; r < 4; ++r) red[w][mt][lane][r] = acc[mt][r];
    __syncthreads();
    for (int idx = tid; idx < 512; idx += 256) {
        int mg = idx >> 4, nn2 = idx & 15;
        int mt = mg >> 4, m = mg & 15;
        int sl = nn2 + 16 * (m >> 2), rg = m & 3;
        float v = red[0][mt][sl][rg] + red[1][mt][sl][rg] + red[2][mt][sl][rg] + red[3][mt][sl][rg];
        int oo = ot * 16 + nn2, b = mg;
        if (oo < HH)
            h_all[(size_t)b * HH + oo] = f2bu(tanh_(v + b_h[oo]));     // h_all[0]
        else
            c_ws[b * HH + (oo - HH)] = tanh_(v + b_c[oo - HH]);
    }
}

// ---------------- Ws = img @ W_att.T + b_att (MFMA, one-shot) -----------------
__global__ __launch_bounds__(256) void k_ws(
    const u16* __restrict__ img_bf, const u16* __restrict__ Watt_bf,
    const float* __restrict__ b_att, u16* __restrict__ Ws_bf)
{
    int bid = blockIdx.x, tid = threadIdx.x;      // 49 mt x 16 nt = 784 blocks
    int mt = bid >> 4, nt = bid & 15;
    int w = tid >> 6, lane = tid & 63, quad = lane >> 4, l16 = lane & 15;
    int rowA = mt * 64 + w * 16 + l16;            // bn index < 3136
    f32x4 acc[2]; acc[0] = {0,0,0,0}; acc[1] = {0,0,0,0};
    const u16* arow = img_bf + (size_t)rowA * EE;
    for (int c = 0; c < 64; ++c) {
        int k = c * 32 + quad * 8;
        bh8 a8 = ld8(arow + k);
        for (int s = 0; s < 2; ++s) {
            bh8 b8 = ld8(Watt_bf + (size_t)(nt * 32 + s * 16 + l16) * EE + k);
            acc[s] = __builtin_amdgcn_mfma_f32_16x16x32_bf16(a8, b8, acc[s], 0, 0, 0);
        }
    }
    for (int s = 0; s < 2; ++s)
        for (int r = 0; r < 4; ++r) {
            int m = quad * 4 + r;
            int row = mt * 64 + w * 16 + m;
            int col = nt * 32 + s * 16 + l16;
            Ws_bf[(size_t)row * HH + col] = f2bu(acc[s][r] + b_att[col]);
        }
}

// ---------------- barrier reset (sync area lives in dead avg_bf region) -------
__global__ void k_zero(unsigned* cnt) {
    int t = threadIdx.x;           // 256 threads zero 1024 u32 (slots + flags)
    cnt[t] = 0; cnt[t + 256] = 0; cnt[t + 512] = 0; cnt[t + 768] = 0;
}

// ---------------- store-slot grid barrier (ZERO atomic RMWs) ------------------
// Arrival: each block STORES its epoch into its own u32 slot (512 slots, 2 KB).
// Independent dword stores to distinct addresses do not serialize like RMWs at
// the coherence point (round-4 post-mortem: 64 RMWs/line ~= 16 us/barrier).
// Detection: block 0's 256 threads each poll 2 slots via one u64 relaxed load +
// __syncthreads_and. Broadcast: 8 read-only flag lines; other blocks poll their
// group's flag (concurrent reads, no convoy). No cache-maintenance anywhere.
__device__ __forceinline__ void gsync(unsigned* cnt, unsigned epoch) {
    __syncthreads();
    const int tid = threadIdx.x, bid = blockIdx.x;
    if (bid == 0) {
        if (tid == 0) stu32_coh(&cnt[0], epoch);          // self-arrival
        const u64* p = reinterpret_cast<const u64*>(cnt) + tid;  // slots 2t, 2t+1
        for (;;) {
            u64 v = __hip_atomic_load(p, __ATOMIC_RELAXED, __HIP_MEMORY_SCOPE_AGENT);
            bool ok = ((unsigned)v >= epoch) && ((unsigned)(v >> 32) >= epoch);
            if (__syncthreads_and(ok)) break;
            __builtin_amdgcn_s_sleep(1);
        }
        if (tid < 8) stu32_coh(&cnt[FLAGOFF + tid * 32], epoch);
        __syncthreads();
    } else {
        if (tid == 0) {
            stu32_coh(&cnt[bid], epoch);                  // arrival store (no RMW)
            while (ldu32_coh(&cnt[FLAGOFF + (bid & 7) * 32]) < epoch)
                __builtin_amdgcn_s_sleep(2);
        }
        __syncthreads();
    }
}

// ---------------- persistent decode loop: phases A (attn), B (LSTM), C (Wu/gate)
// Block->XCD is round-robin (bid % 8). Work mapping keeps each XCD's per-step
// reads L2-resident: A: batch b on XCD b%8 (img_bf 1.6MB + Ws 0.4MB per XCD);
// B: 64 blocks x 64 j-cols; C: 80 blocks x 32 o-cols.
__global__ __launch_bounds__(256, 2) void k_loop(
    const u16* __restrict__ img_bf,
    const u16* __restrict__ Ws_bf,
    float* __restrict__ Wu_ws, float* __restrict__ gate_ws,
    const float* __restrict__ W_v, const float* __restrict__ b_v,
    u16* __restrict__ xctx,
    const u16* __restrict__ emb_all,
    u16* __restrict__ h_all,
    const u16* __restrict__ Wih_bf, const float* __restrict__ b_ih,
    const u16* __restrict__ Whh_bf, const float* __restrict__ b_hh,
    float* __restrict__ c_ws,
    const u16* __restrict__ WU_bf, const float* __restrict__ b_U,
    const u16* __restrict__ Wfb_bf, const float* __restrict__ b_fb,
    unsigned* cnt)
{
    __shared__ float redC[4][2][64][9];   // phase C reduction (pad 8->9)
    __shared__ float redB[4][64][17];     // phase B reduction (pad 16->17)
    __shared__ float wu_sh[HH];           // phase A Wu stage
    __shared__ float part[4][64][3];      // phase A ctx partials (pad 2->3)
    __shared__ float e_sh[NN];            // phase A scores
    __shared__ float a_sh[NN];            // phase A softmax

    const int bid = blockIdx.x, tid = threadIdx.x;
    const int w = tid >> 6, lane = tid & 63, quad = lane >> 4, l16 = lane & 15;
    unsigned snc = 0;

    // ---- phase C: Wu_ws = h@W_U.T + b_U ; gate_ws = sigm(h@W_fb.T + b_fb) ----
    auto phaseC = [&](int tIn) {
        if (bid < 80) {
            int ot = bid;
            const u16* wrow[2];
            #pragma unroll
            for (int s = 0; s < 2; ++s) {
                int o = ot * 32 + s * 16 + l16;
                wrow[s] = (o < HH) ? (WU_bf + (size_t)o * HH)
                                   : (Wfb_bf + (size_t)(o - HH) * HH);
            }
            const u16* hbase = h_all + (size_t)tIn * BB * HH;
            f32x4 acc[2][2];
            for (int mt = 0; mt < 2; ++mt) for (int s = 0; s < 2; ++s) acc[mt][s] = {0,0,0,0};
            for (int c = w * 4; c < w * 4 + 4; ++c) {
                int k = c * 32 + quad * 8;
                bh8 b8[2];
                #pragma unroll
                for (int s = 0; s < 2; ++s) b8[s] = ld8(wrow[s] + k);
                #pragma unroll
                for (int mt = 0; mt < 2; ++mt) {
                    bh8 a8 = ld8_coh(hbase + (size_t)(mt * 16 + l16) * HH + k);
                    #pragma unroll
                    for (int s = 0; s < 2; ++s)
                        acc[mt][s] = __builtin_amdgcn_mfma_f32_16x16x32_bf16(a8, b8[s], acc[mt][s], 0, 0, 0);
                }
            }
            for (int mt = 0; mt < 2; ++mt)
                for (int s = 0; s < 2; ++s)
                    for (int r = 0; r < 4; ++r) redC[w][mt][lane][s * 4 + r] = acc[mt][s][r];
            __syncthreads();
            for (int idx = tid; idx < 1024; idx += 256) {
                int b = idx & 31, col = idx >> 5;         // col 0..31
                int s = col >> 4, nn = col & 15;
                int mt = b >> 4, m = b & 15;
                int sl = (m >> 2) * 16 + nn, rg = s * 4 + (m & 3);
                float v = redC[0][mt][sl][rg] + redC[1][mt][sl][rg]
                        + redC[2][mt][sl][rg] + redC[3][mt][sl][rg];
                int o = ot * 32 + col;
                if (o < HH)
                    stf_coh(&Wu_ws[b * HH + o], v + b_U[o]);
                else
                    stf_coh(&gate_ws[b * EE + (o - HH)], sigm(v + b_fb[o - HH]));
            }
        }
    };

    // ---- phase A: e = Wv.tanh(Ws+Wu)+bv ; softmax ; xctx = gate*ctx ----------
    // All 512 blocks: b = bid&31 (XCD-local batch), s4 = bid>>5 -> 128 ctx cols.
    auto phaseA = [&]() {
        int b = bid & 31, s4 = bid >> 5;
        {   // stage Wu[b] into LDS once (coherent), then read per-lane slices
            float2 t2 = ldf2_coh(Wu_ws + b * HH + tid * 2);
            wu_sh[tid * 2] = t2.x; wu_sh[tid * 2 + 1] = t2.y;
        }
        __syncthreads();
        float wu[8], wv[8];
        #pragma unroll
        for (int j = 0; j < 8; ++j) { wu[j] = wu_sh[lane * 8 + j]; wv[j] = W_v[lane * 8 + j]; }
        for (int n = w; n < NN; n += 4) {
            bh8 ws8 = ld8(Ws_bf + (size_t)(b * NN + n) * HH + lane * 8);
            float acc = 0.f;
            #pragma unroll
            for (int j = 0; j < 8; ++j) acc += wv[j] * tanh_(bsf((u16)ws8[j]) + wu[j]);
            #pragma unroll
            for (int off = 32; off > 0; off >>= 1) acc += __shfl_down(acc, off, 64);
            if (lane == 0) e_sh[n] = acc + b_v[0];
        }
        __syncthreads();
        if (tid < 64) {
            float e0 = e_sh[tid];
            float e1 = (tid + 64 < NN) ? e_sh[tid + 64] : -1e30f;
            float m = fmaxf(e0, e1);
            #pragma unroll
            for (int off = 32; off > 0; off >>= 1) m = fmaxf(m, __shfl_xor(m, off, 64));
            const float L2E = 1.4426950408889634f;
            float x0 = exp2f((e0 - m) * L2E);
            float x1 = (tid + 64 < NN) ? exp2f((e1 - m) * L2E) : 0.f;
            float s = x0 + x1;
            #pragma unroll
            for (int off = 32; off > 0; off >>= 1) s += __shfl_xor(s, off, 64);
            float inv = __builtin_amdgcn_rcpf(s);
            a_sh[tid] = x0 * inv;
            if (tid + 64 < NN) a_sh[tid + 64] = x1 * inv;
        }
        __syncthreads();
        // ctx over 128 cols (s4 tile), n split 4-way across thread groups
        int pc = tid & 63, nq = tid >> 6;
        int c0 = s4 * 128 + pc * 2;
        int n0 = nq * 25, n1 = (nq == 3) ? NN : n0 + 25;
        float a0 = 0.f, a1 = 0.f;
        for (int n = n0; n < n1; ++n) {
            unsigned u = *reinterpret_cast<const unsigned*>(img_bf + (size_t)(b * NN + n) * EE + c0);
            float a = a_sh[n];
            a0 = fmaf(a, bsf(u & 0xffffu), a0);
            a1 = fmaf(a, bsf(u >> 16), a1);
        }
        part[nq][pc][0] = a0; part[nq][pc][1] = a1;
        __syncthreads();
        if (tid < 64) {
            float C0 = part[0][tid][0] + part[1][tid][0] + part[2][tid][0] + part[3][tid][0];
            float C1 = part[0][tid][1] + part[1][tid][1] + part[2][tid][1] + part[3][tid][1];
            int ec = s4 * 128 + tid * 2;
            float2 g = ldf2_coh(gate_ws + b * EE + ec);
            unsigned outw = ((unsigned)f2bu(g.y * C1) << 16) | (unsigned)f2bu(g.x * C0);
            stu32_coh(reinterpret_cast<unsigned*>(xctx + (size_t)b * EE + ec), outw);
        }
    };

    // ---- phase B: gates GEMM (K=3072 concat) + LSTM update -------------------
    // 64 blocks = 2 mt x 32 kt; each block: 16 rows x 64 j-cols (16 k x 4 gates).
    auto phaseB = [&](int t) {
        if (bid < 64) {
            int kt = bid & 31, mt = bid >> 5;
            int brow = mt * 16 + l16;
            const u16* embrow = emb_all + (size_t)(t * BB + brow) * HH;
            const u16* xrow   = xctx + (size_t)brow * EE;
            const u16* hrow   = h_all + (size_t)(t * BB + brow) * HH;
            const u16* wihp[4]; const u16* whhp[4];
            #pragma unroll
            for (int jt = 0; jt < 4; ++jt) {
                int j = kt * 16 + jt * 4 + (l16 & 3) + HH * (l16 >> 2);
                wihp[jt] = Wih_bf + (size_t)j * (HH + EE);
                whhp[jt] = Whh_bf + (size_t)j * HH;
            }
            f32x4 acc[4];
            #pragma unroll
            for (int jt = 0; jt < 4; ++jt) acc[jt] = {0,0,0,0};
            for (int c = w * 24; c < w * 24 + 24; ++c) {   // 96 K-chunks of 32
                int k = c * 32 + quad * 8;
                bh8 a8;
                if (c < 16)      a8 = ld8(embrow + k);
                else if (c < 80) a8 = ld8_coh(xrow + (k - HH));
                else             a8 = ld8_coh(hrow + (k - HH - EE));
                #pragma unroll
                for (int jt = 0; jt < 4; ++jt) {
                    bh8 b8 = (c < 80) ? ld8(wihp[jt] + k) : ld8(whhp[jt] + (k - HH - EE));
                    acc[jt] = __builtin_amdgcn_mfma_f32_16x16x32_bf16(a8, b8, acc[jt], 0, 0, 0);
                }
            }
            for (int jt = 0; jt < 4; ++jt)
                for (int r = 0; r < 4; ++r) redB[w][lane][jt * 4 + r] = acc[jt][r];
            __syncthreads();
            {   // one LSTM cell per thread: (m, kk) of this block's 16x16 tile
                int m = tid >> 4, kk = tid & 15;
                float g4[4];
                #pragma unroll
                for (int g = 0; g < 4; ++g) {
                    int nn = (kk & 3) | (g << 2);
                    int jt = kk >> 2;
                    int sl = (m >> 2) * 16 + nn, rg = m & 3;
                    int jj = kt * 16 + kk + HH * g;
                    g4[g] = redB[0][sl][jt * 4 + rg] + redB[1][sl][jt * 4 + rg]
                          + redB[2][sl][jt * 4 + rg] + redB[3][sl][jt * 4 + rg]
                          + b_ih[jj] + b_hh[jj];
                }
                int b = mt * 16 + m, k = kt * 16 + kk;
                float cold = c_ws[b * HH + k];
                float c2 = sigm(g4[1]) * cold + sigm(g4[0]) * tanh_(g4[2]);
                float h2 = sigm(g4[3]) * tanh_(c2);
                c_ws[b * HH + k] = c2;
                stu16_coh(&h_all[(size_t)((t + 1) * BB + b) * HH + k], f2bu(h2));
            }
        }
    };

    // ---- sequence ------------------------------------------------------------
    phaseC(0);
    gsync(cnt, ++snc);
    for (int t = 0; t < TT; ++t) {
        phaseA();
        gsync(cnt, ++snc);
        phaseB(t);
        gsync(cnt, ++snc);
        if (t < TT - 1) {
            phaseC(t + 1);
            gsync(cnt, ++snc);
        }
    }
}

// ---------------- k_pred: all-step pred = h2 @ W_out.T + b_out (MFMA) ---------
__global__ __launch_bounds__(256) void k_pred(
    const u16* __restrict__ h_all, const u16* __restrict__ Wout_bf,
    const float* __restrict__ b_out, float* __restrict__ out)
{
    int bid = blockIdx.x, tid = threadIdx.x;       // 15 mt(128 rows) x 79 vt(128 v)
    int mt = bid / 79, vt = bid % 79;
    int w = tid >> 6, lane = tid & 63, quad = lane >> 4, l16 = lane & 15;
    f32x4 acc[8][2];
    for (int mi = 0; mi < 8; ++mi) for (int s = 0; s < 2; ++s) acc[mi][s] = {0,0,0,0};
    int nact[2]; int vbase[2];
    for (int s = 0; s < 2; ++s) {
        int ntg = vt * 8 + 2 * w + s;               // 625 total 16-wide v-tiles
        nact[s] = (ntg < 625);
        vbase[s] = ntg * 16;
    }
    for (int c = 0; c < 16; ++c) {
        int k = c * 32 + quad * 8;
        bh8 b8[2];
        for (int s = 0; s < 2; ++s) if (nact[s])
            b8[s] = ld8(Wout_bf + (size_t)(vbase[s] + l16) * HH + k);
        for (int mi = 0; mi < 8; ++mi) {
            int row = 32 + mt * 128 + mi * 16 + l16;   // h2 rows (skip h0 block)
            bh8 a8 = ld8(h_all + (size_t)row * HH + k);
            for (int s = 0; s < 2; ++s) if (nact[s])
                acc[mi][s] = __builtin_amdgcn_mfma_f32_16x16x32_bf16(a8, b8[s], acc[mi][s], 0, 0, 0);
        }
    }
    for (int s = 0; s < 2; ++s) if (nact[s]) {
        int v = vbase[s] + l16;
        float bo = b_out[v];
        for (int mi = 0; mi < 8; ++mi)
            for (int r = 0; r < 4; ++r) {
                int row = 32 + mt * 128 + mi * 16 + quad * 4 + r;
                int tt = (row >> 5) - 1, b = row & 31;
                out[(size_t)(b * TT + tt) * VV + v] = acc[mi][s][r] + bo;
            }
    }
}

extern "C" void kernel_launch(void* const* d_in, const int* in_sizes, int n_in,
                              void* d_out, int out_size, void* d_ws, size_t ws_size,
                              hipStream_t stream)
{
    const float* img      = (const float*)d_in[0];
    const int*   caps     = (const int*)d_in[1];
    const float* emb      = (const float*)d_in[2];
    const float* W_init_h = (const float*)d_in[3];
    const float* b_init_h = (const float*)d_in[4];
    const float* W_init_c = (const float*)d_in[5];
    const float* b_init_c = (const float*)d_in[6];
    const float* W_U      = (const float*)d_in[7];
    const float* b_U      = (const float*)d_in[8];
    const float* W_att    = (const float*)d_in[9];
    const float* b_att    = (const float*)d_in[10];
    const float* W_v      = (const float*)d_in[11];
    const float* b_v      = (const float*)d_in[12];
    const float* W_fb     = (const float*)d_in[13];
    const float* b_fb     = (const float*)d_in[14];
    const float* W_ih     = (const float*)d_in[15];
    const float* b_ih     = (const float*)d_in[16];
    const float* W_hh     = (const float*)d_in[17];
    const float* b_hh     = (const float*)d_in[18];
    const float* W_out    = (const float*)d_in[19];
    const float* b_out    = (const float*)d_in[20];
    float* out = (float*)d_out;

    char* ws = (char*)d_ws;
    u16*   img_bf  = (u16*)(ws);                    // 6,422,528 el -> 12,845,056 B
    u16*   Watt_bf = (u16*)(ws + 12845056);         // 1,048,576 el ->  2,097,152 B
    u16*   Winh_bf = (u16*)(ws + 14942208);         // 1,048,576 el ->  2,097,152 B
    u16*   Winc_bf = (u16*)(ws + 17039360);         // 1,048,576 el ->  2,097,152 B
    u16*   WU_bf   = (u16*)(ws + 19136512);         //   262,144 el ->    524,288 B
    u16*   Wfb_bf  = (u16*)(ws + 19660800);         // 1,048,576 el ->  2,097,152 B
    u16*   Wih_bf  = (u16*)(ws + 21757952);         // 5,242,880 el -> 10,485,760 B
    u16*   Whh_bf  = (u16*)(ws + 32243712);         // 1,048,576 el ->  2,097,152 B
    u16*   Wout_bf = (u16*)(ws + 34340864);         // 5,120,000 el -> 10,240,000 B
    u16*   Ws_bf   = (u16*)(ws + 44580864);         // 3136*512     ->  3,211,264 B
    u16*   emb_all = (u16*)(ws + 47792128);         // 1920*512     ->  1,966,080 B
    u16*   h_all   = (u16*)(ws + 49758208);         // 1952*512     ->  1,998,848 B
    u16*   xctx    = (u16*)(ws + 51757056);         // 32*2048      ->    131,072 B
    u16*   avg_bf  = (u16*)(ws + 51888128);         // 32*2048 (dead after init2; reused for barrier)
    float* c_ws    = (float*)(ws + 52019200);       // 32*512*4     ->     65,536 B
    float* Wu_ws   = (float*)(ws + 52084736);       // 32*512*4     ->     65,536 B
    float* gate_ws = (float*)(ws + 52150272);       // 32*2048*4    ->    262,144 B
    unsigned* sync_cnt = (unsigned*)avg_bf;         // 4 KB inside dead avg_bf region
    // total ws usage: 52,412,416 bytes

    // all fp32 -> bf16 conversions in one launch (dst contiguous at ws base)
    k_conv_all<<<21768, 256, 0, stream>>>(img, W_att, W_init_h, W_init_c, W_U,
                                          W_fb, W_ih, W_hh, W_out, img_bf);

    k_init1<<<496, 256, 0, stream>>>(img, caps, emb, avg_bf, emb_all);
    k_init2<<<64, 256, 0, stream>>>(avg_bf, Winh_bf, b_init_h, Winc_bf, b_init_c, h_all, c_ws);
    k_ws<<<784, 256, 0, stream>>>(img_bf, Watt_bf, b_att, Ws_bf);

    k_zero<<<1, 256, 0, stream>>>(sync_cnt);        // avg_bf is dead from here on
    k_loop<<<NBLK, 256, 0, stream>>>(img_bf, Ws_bf, Wu_ws, gate_ws, W_v, b_v, xctx,
                                     emb_all, h_all, Wih_bf, b_ih, Whh_bf, b_hh, c_ws,
                                     WU_bf, b_U, Wfb_bf, b_fb, sync_cnt);

    k_pred<<<1185, 256, 0, stream>>>(h_all, Wout_bf, b_out, out);
}

// Round 7
// 3681.390 us; speedup vs baseline: 1.0721x; 1.0721x over previous
//
#include <hip/hip_runtime.h>
#include <hip/hip_bf16.h>

// Problem dims
#define BB   32      // batch
#define NN   98      // image regions
#define EE   2048    // img feature dim
#define HH   512     // hidden
#define VV   10000   // vocab
#define TT   60      // timesteps (T_CAP-1)
#define TCAP 61
#define NBLK 512     // persistent-loop grid (2 blocks per CU; co-resident)
#define FLAGOFF 512  // u32 offset of broadcast flag lines in sync area

typedef unsigned short u16;
typedef unsigned long long u64;
typedef __attribute__((ext_vector_type(8))) short bh8;
typedef __attribute__((ext_vector_type(4))) float f32x4;

__device__ __forceinline__ float bsf(unsigned s) {
    union { unsigned u; float f; } w; w.u = s << 16; return w.f;
}
__device__ __forceinline__ u16 f2bu(float f) {
    union { float f; unsigned u; } v; v.f = f;
    unsigned u = v.u;
    u = u + 0x7fffu + ((u >> 16) & 1u);   // RNE
    return (u16)(u >> 16);
}
__device__ __forceinline__ bh8 ld8(const u16* p) {
    return *reinterpret_cast<const bh8*>(p);
}
__device__ __forceinline__ float sigm(float x) {
    return __builtin_amdgcn_rcpf(1.0f + exp2f(-1.4426950408889634f * x));
}
__device__ __forceinline__ float tanh_(float x) {
    return 1.0f - 2.0f * __builtin_amdgcn_rcpf(1.0f + exp2f(2.885390081777927f * x));
}

// ---- producer-side agent-coherent (sc0+sc1, cache-bypassing) stores.
// Consumers use PLAIN CACHED loads: every cross-phase array is t-indexed, so a
// consumer's read is always the FIRST TOUCH of that line on its XCD ->
// guaranteed L2 miss -> fill from L3 (fresh, producer stored sc1) -> all other
// blocks on the XCD hit L2. This removes the round<=5 sc1-consumer-latency wall
// (64 blocks x 5000 uncached L3 round-trips in phase B).
__device__ __forceinline__ void stf_coh(float* p, float v) {
    __hip_atomic_store(p, v, __ATOMIC_RELAXED, __HIP_MEMORY_SCOPE_AGENT);
}
__device__ __forceinline__ void stu16_coh(u16* p, u16 v) {
    __hip_atomic_store(p, v, __ATOMIC_RELAXED, __HIP_MEMORY_SCOPE_AGENT);
}
__device__ __forceinline__ void stu32_coh(unsigned* p, unsigned v) {
    __hip_atomic_store(p, v, __ATOMIC_RELAXED, __HIP_MEMORY_SCOPE_AGENT);
}
__device__ __forceinline__ unsigned ldu32_coh(const unsigned* p) {
    return __hip_atomic_load(p, __ATOMIC_RELAXED, __HIP_MEMORY_SCOPE_AGENT);
}

// ---------------- k_conv_all: all 9 fp32->bf16 conversions in one launch ------
__global__ __launch_bounds__(256) void k_conv_all(
    const float* __restrict__ s_img, const float* __restrict__ s_watt,
    const float* __restrict__ s_winh, const float* __restrict__ s_winc,
    const float* __restrict__ s_wu,  const float* __restrict__ s_wfb,
    const float* __restrict__ s_wih, const float* __restrict__ s_whh,
    const float* __restrict__ s_wout, u16* __restrict__ dst)
{
    size_t i = (size_t)blockIdx.x * 256 + threadIdx.x;   // float4 index
    size_t e = i * 4;                                     // element index
    const float* src; size_t off;
    if      (e <  6422528) { src = s_img;  off = 0; }
    else if (e <  7471104) { src = s_watt; off = 6422528; }
    else if (e <  8519680) { src = s_winh; off = 7471104; }
    else if (e <  9568256) { src = s_winc; off = 8519680; }
    else if (e <  9830400) { src = s_wu;   off = 9568256; }
    else if (e < 10878976) { src = s_wfb;  off = 9830400; }
    else if (e < 16121856) { src = s_wih;  off = 10878976; }
    else if (e < 17170432) { src = s_whh;  off = 16121856; }
    else                   { src = s_wout; off = 17170432; }
    float4 v = reinterpret_cast<const float4*>(src)[(e - off) >> 2];
    ushort4 o;
    o.x = f2bu(v.x); o.y = f2bu(v.y); o.z = f2bu(v.z); o.w = f2bu(v.w);
    reinterpret_cast<ushort4*>(dst)[i] = o;
}

// ---------------- init1: avg features (fp32) + scaled embedding gather --------
__global__ __launch_bounds__(256) void k_init1(
    const float* __restrict__ img, const int* __restrict__ caps,
    const float* __restrict__ emb, u16* __restrict__ avg_bf, u16* __restrict__ emb_all)
{
    int bid = blockIdx.x, tid = threadIdx.x;
    if (bid < 256) {
        int b = bid >> 3, et = bid & 7;
        int ec = et * 256 + tid;
        const float* p = img + (size_t)(b * NN) * EE + ec;
        float s = 0.f;
        for (int n = 0; n < NN; ++n) s += p[(size_t)n * EE];
        avg_bf[b * EE + ec] = f2bu(s * (1.0f / 98.0f));
    } else {
        int eb = bid - 256;                  // 240 blocks x 8 rows = 1920 rows
        for (int r8 = 0; r8 < 8; ++r8) {
            int row = eb * 8 + r8;           // row = t*32 + b
            int t = row >> 5, b = row & 31;
            int cap = caps[b * TCAP + t];
            const float* src = emb + (size_t)cap * HH;
            u16* dst = emb_all + (size_t)row * HH;
            for (int c = tid; c < HH; c += 256)
                dst[c] = f2bu(src[c] * 22.627416997969522f);  // sqrt(512)
        }
    }
}

// ---------------- init2: h0 = tanh(avg@W_init_h.T+b), c0 likewise (MFMA) ------
__global__ __launch_bounds__(256) void k_init2(
    const u16* __restrict__ avg_bf,
    const u16* __restrict__ Wh_bf, const float* __restrict__ b_h,
    const u16* __restrict__ Wc_bf, const float* __restrict__ b_c,
    u16* __restrict__ h_all, float* __restrict__ c_ws)
{
    __shared__ float red[4][2][64][4];
    int ot = blockIdx.x, tid = threadIdx.x;       // 64 blocks x 16 outputs (1024 total)
    int w = tid >> 6, lane = tid & 63, quad = lane >> 4, l16 = lane & 15;
    int o = ot * 16 + l16;
    const u16* wrow = (o < HH) ? (Wh_bf + (size_t)o * EE) : (Wc_bf + (size_t)(o - HH) * EE);
    f32x4 acc[2]; acc[0] = {0,0,0,0}; acc[1] = {0,0,0,0};
    for (int c = w * 16; c < w * 16 + 16; ++c) {
        int k = c * 32 + quad * 8;
        bh8 b8 = ld8(wrow + k);
        for (int mt = 0; mt < 2; ++mt) {
            bh8 a8 = ld8(avg_bf + (size_t)(mt * 16 + l16) * EE + k);
            acc[mt] = __builtin_amdgcn_mfma_f32_16x16x32_bf16(a8, b8, acc[mt], 0, 0, 0);
        }
    }
    for (int mt = 0; mt < 2; ++mt)
        for (int r = 0; r < 4; ++r) red[w][mt][lane][r] = acc[mt][r];
    __syncthreads();
    for (int idx = tid; idx < 512; idx += 256) {
        int mg = idx >> 4, nn2 = idx & 15;
        int mt = mg >> 4, m = mg & 15;
        int sl = nn2 + 16 * (m >> 2), rg = m & 3;
        float v = red[0][mt][sl][rg] + red[1][mt][sl][rg] + red[2][mt][sl][rg] + red[3][mt][sl][rg];
        int oo = ot * 16 + nn2, b = mg;
        if (oo < HH)
            h_all[(size_t)b * HH + oo] = f2bu(tanh_(v + b_h[oo]));     // h_all[0]
        else
            c_ws[b * HH + (oo - HH)] = tanh_(v + b_c[oo - HH]);
    }
}

// ---------------- Ws = img @ W_att.T + b_att (MFMA, one-shot) -----------------
__global__ __launch_bounds__(256) void k_ws(
    const u16* __restrict__ img_bf, const u16* __restrict__ Watt_bf,
    const float* __restrict__ b_att, u16* __restrict__ Ws_bf)
{
    int bid = blockIdx.x, tid = threadIdx.x;      // 49 mt x 16 nt = 784 blocks
    int mt = bid >> 4, nt = bid & 15;
    int w = tid >> 6, lane = tid & 63, quad = lane >> 4, l16 = lane & 15;
    int rowA = mt * 64 + w * 16 + l16;            // bn index < 3136
    f32x4 acc[2]; acc[0] = {0,0,0,0}; acc[1] = {0,0,0,0};
    const u16* arow = img_bf + (size_t)rowA * EE;
    for (int c = 0; c < 64; ++c) {
        int k = c * 32 + quad * 8;
        bh8 a8 = ld8(arow + k);
        for (int s = 0; s < 2; ++s) {
            bh8 b8 = ld8(Watt_bf + (size_t)(nt * 32 + s * 16 + l16) * EE + k);
            acc[s] = __builtin_amdgcn_mfma_f32_16x16x32_bf16(a8, b8, acc[s], 0, 0, 0);
        }
    }
    for (int s = 0; s < 2; ++s)
        for (int r = 0; r < 4; ++r) {
            int m = quad * 4 + r;
            int row = mt * 64 + w * 16 + m;
            int col = nt * 32 + s * 16 + l16;
            Ws_bf[(size_t)row * HH + col] = f2bu(acc[s][r] + b_att[col]);
        }
}

// ---------------- barrier reset (sync area lives in dead avg_bf region) -------
__global__ void k_zero(unsigned* cnt) {
    int t = threadIdx.x;           // 256 threads zero 1024 u32 (slots + flags)
    cnt[t] = 0; cnt[t + 256] = 0; cnt[t + 512] = 0; cnt[t + 768] = 0;
}

// ---------------- store-slot grid barrier (round-5, proven) -------------------
__device__ __forceinline__ void gsync(unsigned* cnt, unsigned epoch) {
    __syncthreads();
    const int tid = threadIdx.x, bid = blockIdx.x;
    if (bid == 0) {
        if (tid == 0) stu32_coh(&cnt[0], epoch);          // self-arrival
        const u64* p = reinterpret_cast<const u64*>(cnt) + tid;  // slots 2t, 2t+1
        for (;;) {
            u64 v = __hip_atomic_load(p, __ATOMIC_RELAXED, __HIP_MEMORY_SCOPE_AGENT);
            bool ok = ((unsigned)v >= epoch) && ((unsigned)(v >> 32) >= epoch);
            if (__syncthreads_and(ok)) break;
            __builtin_amdgcn_s_sleep(1);
        }
        if (tid < 8) stu32_coh(&cnt[FLAGOFF + tid * 32], epoch);
        __syncthreads();
    } else {
        if (tid == 0) {
            stu32_coh(&cnt[bid], epoch);                  // arrival store (no RMW)
            while (ldu32_coh(&cnt[FLAGOFF + (bid & 7) * 32]) < epoch)
                __builtin_amdgcn_s_sleep(2);
        }
        __syncthreads();
    }
}

// ---------------- persistent decode loop: phases A (attn), B (LSTM), C (Wu/gate)
// Cross-phase data is t-indexed: producers store sc1 (to L3), consumers do
// PLAIN CACHED loads (first touch per XCD per step -> L2 fill from L3, then
// L2 hits for all sibling blocks on the XCD).
__global__ __launch_bounds__(256, 2) void k_loop(
    const u16* __restrict__ img_bf,
    const u16* __restrict__ Ws_bf,
    float* __restrict__ Wu_all, float* __restrict__ gate_all,
    const float* __restrict__ W_v, const float* __restrict__ b_v,
    u16* __restrict__ xctx_all,
    const u16* __restrict__ emb_all,
    u16* __restrict__ h_all,
    const u16* __restrict__ Wih_bf, const float* __restrict__ b_ih,
    const u16* __restrict__ Whh_bf, const float* __restrict__ b_hh,
    float* __restrict__ c_ws,
    const u16* __restrict__ WU_bf, const float* __restrict__ b_U,
    const u16* __restrict__ Wfb_bf, const float* __restrict__ b_fb,
    unsigned* cnt)
{
    __shared__ float redC[4][2][64][9];   // phase C reduction (pad 8->9)
    __shared__ float redB[4][64][17];     // phase B reduction (pad 16->17)
    __shared__ float wu_sh[HH];           // phase A Wu stage
    __shared__ float part[4][64][3];      // phase A ctx partials (pad 2->3)
    __shared__ float e_sh[NN];            // phase A scores
    __shared__ float a_sh[NN];            // phase A softmax

    const int bid = blockIdx.x, tid = threadIdx.x;
    const int w = tid >> 6, lane = tid & 63, quad = lane >> 4, l16 = lane & 15;
    unsigned snc = 0;

    // ---- phase C: Wu_all[t] = h@W_U.T + b_U ; gate_all[t] = sigm(h@W_fb.T+b) -
    // h_all[tIn]: plain cached reads (t-indexed, first touch). Outputs: sc1.
    auto phaseC = [&](int tIn) {
        if (bid < 80) {
            int ot = bid;
            const u16* wrow[2];
            #pragma unroll
            for (int s = 0; s < 2; ++s) {
                int o = ot * 32 + s * 16 + l16;
                wrow[s] = (o < HH) ? (WU_bf + (size_t)o * HH)
                                   : (Wfb_bf + (size_t)(o - HH) * HH);
            }
            const u16* hbase = h_all + (size_t)tIn * BB * HH;
            f32x4 acc[2][2];
            for (int mt = 0; mt < 2; ++mt) for (int s = 0; s < 2; ++s) acc[mt][s] = {0,0,0,0};
            for (int c = w * 4; c < w * 4 + 4; ++c) {
                int k = c * 32 + quad * 8;
                bh8 b8[2];
                #pragma unroll
                for (int s = 0; s < 2; ++s) b8[s] = ld8(wrow[s] + k);
                #pragma unroll
                for (int mt = 0; mt < 2; ++mt) {
                    bh8 a8 = ld8(hbase + (size_t)(mt * 16 + l16) * HH + k);   // cached
                    #pragma unroll
                    for (int s = 0; s < 2; ++s)
                        acc[mt][s] = __builtin_amdgcn_mfma_f32_16x16x32_bf16(a8, b8[s], acc[mt][s], 0, 0, 0);
                }
            }
            for (int mt = 0; mt < 2; ++mt)
                for (int s = 0; s < 2; ++s)
                    for (int r = 0; r < 4; ++r) redC[w][mt][lane][s * 4 + r] = acc[mt][s][r];
            __syncthreads();
            for (int idx = tid; idx < 1024; idx += 256) {
                int b = idx & 31, col = idx >> 5;         // col 0..31
                int s = col >> 4, nn = col & 15;
                int mt = b >> 4, m = b & 15;
                int sl = (m >> 2) * 16 + nn, rg = s * 4 + (m & 3);
                float v = redC[0][mt][sl][rg] + redC[1][mt][sl][rg]
                        + redC[2][mt][sl][rg] + redC[3][mt][sl][rg];
                int o = ot * 32 + col;
                if (o < HH)
                    stf_coh(&Wu_all[((size_t)tIn * BB + b) * HH + o], v + b_U[o]);
                else
                    stf_coh(&gate_all[((size_t)tIn * BB + b) * EE + (o - HH)], sigm(v + b_fb[o - HH]));
            }
        }
    };

    // ---- phase A: e = Wv.tanh(Ws+Wu)+bv ; softmax ; xctx = gate*ctx ----------
    // All 512 blocks: b = bid&31 (all 16 blocks of batch b land on XCD b%8),
    // s4 = bid>>5 -> 128 ctx cols. Wu/gate: plain cached reads (t-indexed).
    auto phaseA = [&](int t) {
        int b = bid & 31, s4 = bid >> 5;
        const float* wubase = Wu_all + ((size_t)t * BB + b) * HH;
        {   // stage Wu[t][b] into LDS (cached reads; 1 fill + 15 L2 hits/XCD)
            float2 t2 = *reinterpret_cast<const float2*>(wubase + tid * 2);
            wu_sh[tid * 2] = t2.x; wu_sh[tid * 2 + 1] = t2.y;
        }
        __syncthreads();
        float wu[8], wv[8];
        #pragma unroll
        for (int j = 0; j < 8; ++j) { wu[j] = wu_sh[lane * 8 + j]; wv[j] = W_v[lane * 8 + j]; }
        for (int n = w; n < NN; n += 4) {
            bh8 ws8 = ld8(Ws_bf + (size_t)(b * NN + n) * HH + lane * 8);
            float acc = 0.f;
            #pragma unroll
            for (int j = 0; j < 8; ++j) acc += wv[j] * tanh_(bsf((u16)ws8[j]) + wu[j]);
            #pragma unroll
            for (int off = 32; off > 0; off >>= 1) acc += __shfl_down(acc, off, 64);
            if (lane == 0) e_sh[n] = acc + b_v[0];
        }
        __syncthreads();
        if (tid < 64) {
            float e0 = e_sh[tid];
            float e1 = (tid + 64 < NN) ? e_sh[tid + 64] : -1e30f;
            float m = fmaxf(e0, e1);
            #pragma unroll
            for (int off = 32; off > 0; off >>= 1) m = fmaxf(m, __shfl_xor(m, off, 64));
            const float L2E = 1.4426950408889634f;
            float x0 = exp2f((e0 - m) * L2E);
            float x1 = (tid + 64 < NN) ? exp2f((e1 - m) * L2E) : 0.f;
            float s = x0 + x1;
            #pragma unroll
            for (int off = 32; off > 0; off >>= 1) s += __shfl_xor(s, off, 64);
            float inv = __builtin_amdgcn_rcpf(s);
            a_sh[tid] = x0 * inv;
            if (tid + 64 < NN) a_sh[tid + 64] = x1 * inv;
        }
        __syncthreads();
        // ctx over 128 cols (s4 tile), n split 4-way across thread groups
        int pc = tid & 63, nq = tid >> 6;
        int c0 = s4 * 128 + pc * 2;
        int n0 = nq * 25, n1 = (nq == 3) ? NN : n0 + 25;
        float a0 = 0.f, a1 = 0.f;
        for (int n = n0; n < n1; ++n) {
            unsigned u = *reinterpret_cast<const unsigned*>(img_bf + (size_t)(b * NN + n) * EE + c0);
            float a = a_sh[n];
            a0 = fmaf(a, bsf(u & 0xffffu), a0);
            a1 = fmaf(a, bsf(u >> 16), a1);
        }
        part[nq][pc][0] = a0; part[nq][pc][1] = a1;
        __syncthreads();
        if (tid < 64) {
            float C0 = part[0][tid][0] + part[1][tid][0] + part[2][tid][0] + part[3][tid][0];
            float C1 = part[0][tid][1] + part[1][tid][1] + part[2][tid][1] + part[3][tid][1];
            int ec = s4 * 128 + tid * 2;
            float2 g = *reinterpret_cast<const float2*>(
                gate_all + ((size_t)t * BB + b) * EE + ec);               // cached
            unsigned outw = ((unsigned)f2bu(g.y * C1) << 16) | (unsigned)f2bu(g.x * C0);
            stu32_coh(reinterpret_cast<unsigned*>(
                xctx_all + ((size_t)t * BB + b) * EE + ec), outw);        // sc1
        }
    };

    // ---- phase B: gates GEMM (K=3072 concat) + LSTM update -------------------
    // 64 blocks = 2 mt x 32 kt. xctx_all[t]/h_all[t]: plain cached reads.
    auto phaseB = [&](int t) {
        if (bid < 64) {
            int kt = bid & 31, mt = bid >> 5;
            int brow = mt * 16 + l16;
            const u16* embrow = emb_all + (size_t)(t * BB + brow) * HH;
            const u16* xrow   = xctx_all + ((size_t)t * BB + brow) * EE;
            const u16* hrow   = h_all + (size_t)(t * BB + brow) * HH;
            const u16* wihp[4]; const u16* whhp[4];
            #pragma unroll
            for (int jt = 0; jt < 4; ++jt) {
                int j = kt * 16 + jt * 4 + (l16 & 3) + HH * (l16 >> 2);
                wihp[jt] = Wih_bf + (size_t)j * (HH + EE);
                whhp[jt] = Whh_bf + (size_t)j * HH;
            }
            f32x4 acc[4];
            #pragma unroll
            for (int jt = 0; jt < 4; ++jt) acc[jt] = {0,0,0,0};
            for (int c = w * 24; c < w * 24 + 24; ++c) {   // 96 K-chunks of 32
                int k = c * 32 + quad * 8;
                bh8 a8;
                if (c < 16)      a8 = ld8(embrow + k);
                else if (c < 80) a8 = ld8(xrow + (k - HH));          // cached
                else             a8 = ld8(hrow + (k - HH - EE));     // cached
                #pragma unroll
                for (int jt = 0; jt < 4; ++jt) {
                    bh8 b8 = (c < 80) ? ld8(wihp[jt] + k) : ld8(whhp[jt] + (k - HH - EE));
                    acc[jt] = __builtin_amdgcn_mfma_f32_16x16x32_bf16(a8, b8, acc[jt], 0, 0, 0);
                }
            }
            for (int jt = 0; jt < 4; ++jt)
                for (int r = 0; r < 4; ++r) redB[w][lane][jt * 4 + r] = acc[jt][r];
            __syncthreads();
            {   // one LSTM cell per thread: (m, kk) of this block's 16x16 tile
                int m = tid >> 4, kk = tid & 15;
                float g4[4];
                #pragma unroll
                for (int g = 0; g < 4; ++g) {
                    int nn = (kk & 3) | (g << 2);
                    int jt = kk >> 2;
                    int sl = (m >> 2) * 16 + nn, rg = m & 3;
                    int jj = kt * 16 + kk + HH * g;
                    g4[g] = redB[0][sl][jt * 4 + rg] + redB[1][sl][jt * 4 + rg]
                          + redB[2][sl][jt * 4 + rg] + redB[3][sl][jt * 4 + rg]
                          + b_ih[jj] + b_hh[jj];
                }
                int b = mt * 16 + m, k = kt * 16 + kk;
                float cold = c_ws[b * HH + k];
                float c2 = sigm(g4[1]) * cold + sigm(g4[0]) * tanh_(g4[2]);
                float h2 = sigm(g4[3]) * tanh_(c2);
                c_ws[b * HH + k] = c2;
                stu16_coh(&h_all[(size_t)((t + 1) * BB + b) * HH + k], f2bu(h2));  // sc1
            }
        }
    };

    // ---- sequence ------------------------------------------------------------
    phaseC(0);
    gsync(cnt, ++snc);
    for (int t = 0; t < TT; ++t) {
        phaseA(t);
        gsync(cnt, ++snc);
        phaseB(t);
        gsync(cnt, ++snc);
        if (t < TT - 1) {
            phaseC(t + 1);
            gsync(cnt, ++snc);
        }
    }
}

// ---------------- k_pred: all-step pred = h2 @ W_out.T + b_out (MFMA) ---------
__global__ __launch_bounds__(256) void k_pred(
    const u16* __restrict__ h_all, const u16* __restrict__ Wout_bf,
    const float* __restrict__ b_out, float* __restrict__ out)
{
    int bid = blockIdx.x, tid = threadIdx.x;       // 15 mt(128 rows) x 79 vt(128 v)
    int mt = bid / 79, vt = bid % 79;
    int w = tid >> 6, lane = tid & 63, quad = lane >> 4, l16 = lane & 15;
    f32x4 acc[8][2];
    for (int mi = 0; mi < 8; ++mi) for (int s = 0; s < 2; ++s) acc[mi][s] = {0,0,0,0};
    int nact[2]; int vbase[2];
    for (int s = 0; s < 2; ++s) {
        int ntg = vt * 8 + 2 * w + s;               // 625 total 16-wide v-tiles
        nact[s] = (ntg < 625);
        vbase[s] = ntg * 16;
    }
    for (int c = 0; c < 16; ++c) {
        int k = c * 32 + quad * 8;
        bh8 b8[2];
        for (int s = 0; s < 2; ++s) if (nact[s])
            b8[s] = ld8(Wout_bf + (size_t)(vbase[s] + l16) * HH + k);
        for (int mi = 0; mi < 8; ++mi) {
            int row = 32 + mt * 128 + mi * 16 + l16;   // h2 rows (skip h0 block)
            bh8 a8 = ld8(h_all + (size_t)row * HH + k);
            for (int s = 0; s < 2; ++s) if (nact[s])
                acc[mi][s] = __builtin_amdgcn_mfma_f32_16x16x32_bf16(a8, b8[s], acc[mi][s], 0, 0, 0);
        }
    }
    for (int s = 0; s < 2; ++s) if (nact[s]) {
        int v = vbase[s] + l16;
        float bo = b_out[v];
        for (int mi = 0; mi < 8; ++mi)
            for (int r = 0; r < 4; ++r) {
                int row = 32 + mt * 128 + mi * 16 + quad * 4 + r;
                int tt = (row >> 5) - 1, b = row & 31;
                out[(size_t)(b * TT + tt) * VV + v] = acc[mi][s][r] + bo;
            }
    }
}

extern "C" void kernel_launch(void* const* d_in, const int* in_sizes, int n_in,
                              void* d_out, int out_size, void* d_ws, size_t ws_size,
                              hipStream_t stream)
{
    const float* img      = (const float*)d_in[0];
    const int*   caps     = (const int*)d_in[1];
    const float* emb      = (const float*)d_in[2];
    const float* W_init_h = (const float*)d_in[3];
    const float* b_init_h = (const float*)d_in[4];
    const float* W_init_c = (const float*)d_in[5];
    const float* b_init_c = (const float*)d_in[6];
    const float* W_U      = (const float*)d_in[7];
    const float* b_U      = (const float*)d_in[8];
    const float* W_att    = (const float*)d_in[9];
    const float* b_att    = (const float*)d_in[10];
    const float* W_v      = (const float*)d_in[11];
    const float* b_v      = (const float*)d_in[12];
    const float* W_fb     = (const float*)d_in[13];
    const float* b_fb     = (const float*)d_in[14];
    const float* W_ih     = (const float*)d_in[15];
    const float* b_ih     = (const float*)d_in[16];
    const float* W_hh     = (const float*)d_in[17];
    const float* b_hh     = (const float*)d_in[18];
    const float* W_out    = (const float*)d_in[19];
    const float* b_out    = (const float*)d_in[20];
    float* out = (float*)d_out;

    char* ws = (char*)d_ws;
    u16*   img_bf   = (u16*)(ws);                    // 12,845,056 B
    u16*   Watt_bf  = (u16*)(ws + 12845056);         //  2,097,152 B
    u16*   Winh_bf  = (u16*)(ws + 14942208);         //  2,097,152 B
    u16*   Winc_bf  = (u16*)(ws + 17039360);         //  2,097,152 B
    u16*   WU_bf    = (u16*)(ws + 19136512);         //    524,288 B
    u16*   Wfb_bf   = (u16*)(ws + 19660800);         //  2,097,152 B
    u16*   Wih_bf   = (u16*)(ws + 21757952);         // 10,485,760 B
    u16*   Whh_bf   = (u16*)(ws + 32243712);         //  2,097,152 B
    u16*   Wout_bf  = (u16*)(ws + 34340864);         // 10,240,000 B
    u16*   Ws_bf    = (u16*)(ws + 44580864);         //  3,211,264 B
    u16*   emb_all  = (u16*)(ws + 47792128);         //  1,966,080 B
    u16*   h_all    = (u16*)(ws + 49758208);         //  1,998,848 B (61x32x512 u16)
    u16*   avg_bf   = (u16*)(ws + 51757056);         //    131,072 B (dead after init2 -> sync)
    float* c_ws     = (float*)(ws + 51888128);       //     65,536 B
    u16*   xctx_all = (u16*)(ws + 51953664);         //  7,995,392 B (61x32x2048 u16)
    float* Wu_all   = (float*)(ws + 59949056);       //  3,997,696 B (61x32x512 f32)
    float* gate_all = (float*)(ws + 63946752);       // 15,990,784 B (61x32x2048 f32)
    unsigned* sync_cnt = (unsigned*)avg_bf;          // 4 KB inside dead avg_bf region
    // total ws usage: 79,937,536 bytes

    // all fp32 -> bf16 conversions in one launch (dst contiguous at ws base)
    k_conv_all<<<21768, 256, 0, stream>>>(img, W_att, W_init_h, W_init_c, W_U,
                                          W_fb, W_ih, W_hh, W_out, img_bf);

    k_init1<<<496, 256, 0, stream>>>(img, caps, emb, avg_bf, emb_all);
    k_init2<<<64, 256, 0, stream>>>(avg_bf, Winh_bf, b_init_h, Winc_bf, b_init_c, h_all, c_ws);
    k_ws<<<784, 256, 0, stream>>>(img_bf, Watt_bf, b_att, Ws_bf);

    k_zero<<<1, 256, 0, stream>>>(sync_cnt);        // avg_bf is dead from here on
    k_loop<<<NBLK, 256, 0, stream>>>(img_bf, Ws_bf, Wu_all, gate_all, W_v, b_v, xctx_all,
                                     emb_all, h_all, Wih_bf, b_ih, Whh_bf, b_hh, c_ws,
                                     WU_bf, b_U, Wfb_bf, b_fb, sync_cnt);

    k_pred<<<1185, 256, 0, stream>>>(h_all, Wout_bf, b_out, out);
}

// Round 8
// 2945.131 us; speedup vs baseline: 1.3402x; 1.2500x over previous
//
#include <hip/hip_runtime.h>
#include <hip/hip_bf16.h>

// Problem dims
#define BB   32      // batch
#define NN   98      // image regions
#define EE   2048    // img feature dim
#define HH   512     // hidden
#define VV   10000   // vocab
#define TT   60      // timesteps (T_CAP-1)
#define TCAP 61
#define NBLK 256     // persistent-loop grid (1 block per CU)
#define FLG  512     // u32 index of per-block flag lines: cnt[FLG + bid*32]

typedef unsigned short u16;
typedef unsigned long long u64;
typedef __attribute__((ext_vector_type(8))) short bh8;
typedef __attribute__((ext_vector_type(4))) float f32x4;

__device__ __forceinline__ float bsf(unsigned s) {
    union { unsigned u; float f; } w; w.u = s << 16; return w.f;
}
__device__ __forceinline__ u16 f2bu(float f) {
    union { float f; unsigned u; } v; v.f = f;
    unsigned u = v.u;
    u = u + 0x7fffu + ((u >> 16) & 1u);   // RNE
    return (u16)(u >> 16);
}
__device__ __forceinline__ bh8 ld8(const u16* p) {
    return *reinterpret_cast<const bh8*>(p);
}
__device__ __forceinline__ float sigm(float x) {
    return __builtin_amdgcn_rcpf(1.0f + exp2f(-1.4426950408889634f * x));
}
__device__ __forceinline__ float tanh_(float x) {
    return 1.0f - 2.0f * __builtin_amdgcn_rcpf(1.0f + exp2f(2.885390081777927f * x));
}

// ---- producer-side agent-coherent (sc0+sc1, cache-bypassing) stores.
// Consumers use PLAIN CACHED loads on t-indexed arrays (first touch per XCD
// per step -> L2 fill from L3 where the producer's sc1 store landed).
__device__ __forceinline__ void stf_coh(float* p, float v) {
    __hip_atomic_store(p, v, __ATOMIC_RELAXED, __HIP_MEMORY_SCOPE_AGENT);
}
__device__ __forceinline__ void stu16_coh(u16* p, u16 v) {
    __hip_atomic_store(p, v, __ATOMIC_RELAXED, __HIP_MEMORY_SCOPE_AGENT);
}
__device__ __forceinline__ void stu32_coh(unsigned* p, unsigned v) {
    __hip_atomic_store(p, v, __ATOMIC_RELAXED, __HIP_MEMORY_SCOPE_AGENT);
}
__device__ __forceinline__ unsigned ldu32_coh(const unsigned* p) {
    return __hip_atomic_load(p, __ATOMIC_RELAXED, __HIP_MEMORY_SCOPE_AGENT);
}

// ---------------- k_conv_all: all 9 fp32->bf16 conversions in one launch ------
__global__ __launch_bounds__(256) void k_conv_all(
    const float* __restrict__ s_img, const float* __restrict__ s_watt,
    const float* __restrict__ s_winh, const float* __restrict__ s_winc,
    const float* __restrict__ s_wu,  const float* __restrict__ s_wfb,
    const float* __restrict__ s_wih, const float* __restrict__ s_whh,
    const float* __restrict__ s_wout, u16* __restrict__ dst)
{
    size_t i = (size_t)blockIdx.x * 256 + threadIdx.x;   // float4 index
    size_t e = i * 4;                                     // element index
    const float* src; size_t off;
    if      (e <  6422528) { src = s_img;  off = 0; }
    else if (e <  7471104) { src = s_watt; off = 6422528; }
    else if (e <  8519680) { src = s_winh; off = 7471104; }
    else if (e <  9568256) { src = s_winc; off = 8519680; }
    else if (e <  9830400) { src = s_wu;   off = 9568256; }
    else if (e < 10878976) { src = s_wfb;  off = 9830400; }
    else if (e < 16121856) { src = s_wih;  off = 10878976; }
    else if (e < 17170432) { src = s_whh;  off = 16121856; }
    else                   { src = s_wout; off = 17170432; }
    float4 v = reinterpret_cast<const float4*>(src)[(e - off) >> 2];
    ushort4 o;
    o.x = f2bu(v.x); o.y = f2bu(v.y); o.z = f2bu(v.z); o.w = f2bu(v.w);
    reinterpret_cast<ushort4*>(dst)[i] = o;
}

// ---------------- init1: avg features (fp32) + scaled embedding gather --------
__global__ __launch_bounds__(256) void k_init1(
    const float* __restrict__ img, const int* __restrict__ caps,
    const float* __restrict__ emb, u16* __restrict__ avg_bf, u16* __restrict__ emb_all)
{
    int bid = blockIdx.x, tid = threadIdx.x;
    if (bid < 256) {
        int b = bid >> 3, et = bid & 7;
        int ec = et * 256 + tid;
        const float* p = img + (size_t)(b * NN) * EE + ec;
        float s = 0.f;
        for (int n = 0; n < NN; ++n) s += p[(size_t)n * EE];
        avg_bf[b * EE + ec] = f2bu(s * (1.0f / 98.0f));
    } else {
        int eb = bid - 256;                  // 240 blocks x 8 rows = 1920 rows
        for (int r8 = 0; r8 < 8; ++r8) {
            int row = eb * 8 + r8;           // row = t*32 + b
            int t = row >> 5, b = row & 31;
            int cap = caps[b * TCAP + t];
            const float* src = emb + (size_t)cap * HH;
            u16* dst = emb_all + (size_t)row * HH;
            for (int c = tid; c < HH; c += 256)
                dst[c] = f2bu(src[c] * 22.627416997969522f);  // sqrt(512)
        }
    }
}

// ---------------- init2: h0 = tanh(avg@W_init_h.T+b), c0 likewise (MFMA) ------
__global__ __launch_bounds__(256) void k_init2(
    const u16* __restrict__ avg_bf,
    const u16* __restrict__ Wh_bf, const float* __restrict__ b_h,
    const u16* __restrict__ Wc_bf, const float* __restrict__ b_c,
    u16* __restrict__ h_all, float* __restrict__ c_ws)
{
    __shared__ float red[4][2][64][4];
    int ot = blockIdx.x, tid = threadIdx.x;       // 64 blocks x 16 outputs (1024 total)
    int w = tid >> 6, lane = tid & 63, quad = lane >> 4, l16 = lane & 15;
    int o = ot * 16 + l16;
    const u16* wrow = (o < HH) ? (Wh_bf + (size_t)o * EE) : (Wc_bf + (size_t)(o - HH) * EE);
    f32x4 acc[2]; acc[0] = {0,0,0,0}; acc[1] = {0,0,0,0};
    for (int c = w * 16; c < w * 16 + 16; ++c) {
        int k = c * 32 + quad * 8;
        bh8 b8 = ld8(wrow + k);
        for (int mt = 0; mt < 2; ++mt) {
            bh8 a8 = ld8(avg_bf + (size_t)(mt * 16 + l16) * EE + k);
            acc[mt] = __builtin_amdgcn_mfma_f32_16x16x32_bf16(a8, b8, acc[mt], 0, 0, 0);
        }
    }
    for (int mt = 0; mt < 2; ++mt)
        for (int r = 0; r < 4; ++r) red[w][mt][lane][r] = acc[mt][r];
    __syncthreads();
    for (int idx = tid; idx < 512; idx += 256) {
        int mg = idx >> 4, nn2 = idx & 15;
        int mt = mg >> 4, m = mg & 15;
        int sl = nn2 + 16 * (m >> 2), rg = m & 3;
        float v = red[0][mt][sl][rg] + red[1][mt][sl][rg] + red[2][mt][sl][rg] + red[3][mt][sl][rg];
        int oo = ot * 16 + nn2, b = mg;
        if (oo < HH)
            h_all[(size_t)b * HH + oo] = f2bu(tanh_(v + b_h[oo]));     // h_all[0]
        else
            c_ws[b * HH + (oo - HH)] = tanh_(v + b_c[oo - HH]);
    }
}

// ---------------- Ws = img @ W_att.T + b_att (MFMA, one-shot) -----------------
__global__ __launch_bounds__(256) void k_ws(
    const u16* __restrict__ img_bf, const u16* __restrict__ Watt_bf,
    const float* __restrict__ b_att, u16* __restrict__ Ws_bf)
{
    int bid = blockIdx.x, tid = threadIdx.x;      // 49 mt x 16 nt = 784 blocks
    int mt = bid >> 4, nt = bid & 15;
    int w = tid >> 6, lane = tid & 63, quad = lane >> 4, l16 = lane & 15;
    int rowA = mt * 64 + w * 16 + l16;            // bn index < 3136
    f32x4 acc[2]; acc[0] = {0,0,0,0}; acc[1] = {0,0,0,0};
    const u16* arow = img_bf + (size_t)rowA * EE;
    for (int c = 0; c < 64; ++c) {
        int k = c * 32 + quad * 8;
        bh8 a8 = ld8(arow + k);
        for (int s = 0; s < 2; ++s) {
            bh8 b8 = ld8(Watt_bf + (size_t)(nt * 32 + s * 16 + l16) * EE + k);
            acc[s] = __builtin_amdgcn_mfma_f32_16x16x32_bf16(a8, b8, acc[s], 0, 0, 0);
        }
    }
    for (int s = 0; s < 2; ++s)
        for (int r = 0; r < 4; ++r) {
            int m = quad * 4 + r;
            int row = mt * 64 + w * 16 + m;
            int col = nt * 32 + s * 16 + l16;
            Ws_bf[(size_t)row * HH + col] = f2bu(acc[s][r] + b_att[col]);
        }
}

// ---------------- barrier reset (sync area lives in dead avg_bf region) -------
__global__ void k_zero(unsigned* cnt) {
    int t = threadIdx.x;           // zero 256 slots + 256 flag lines (9216 u32)
    for (int i = 0; i < 36; ++i) stu32_coh(&cnt[t + i * 256], 0u);
}

// ---------------- grid barrier: store-slot arrival + PER-BLOCK private flags --
// Arrival: each block STOREs its epoch into its own slot (no RMW; proven R5).
// Detection: block 0's 128 lanes each poll one u64 (2 slots) + syncthreads_and.
// Release: block 0's 256 threads store 256 SEPARATE flag lines (128 B apart).
// Each flag line has exactly ONE writer (block 0) and ONE reader (its block's
// tid0) -> no same-line multi-poller convoy anywhere (the R4-R7 invariant).
__device__ __forceinline__ void gsync(unsigned* cnt, unsigned epoch) {
    __syncthreads();
    const int tid = threadIdx.x, bid = blockIdx.x;
    if (bid == 0) {
        if (tid == 0) stu32_coh(&cnt[0], epoch);          // self-arrival
        const u64* p = reinterpret_cast<const u64*>(cnt) + tid;  // slots 2t,2t+1
        for (;;) {
            bool ok = true;
            if (tid < 128) {
                u64 v = __hip_atomic_load(p, __ATOMIC_RELAXED, __HIP_MEMORY_SCOPE_AGENT);
                ok = ((unsigned)v >= epoch) && ((unsigned)(v >> 32) >= epoch);
            }
            if (__syncthreads_and(ok)) break;
            __builtin_amdgcn_s_sleep(1);
        }
        stu32_coh(&cnt[FLG + tid * 32], epoch);           // 256 private flags
        __syncthreads();
    } else {
        if (tid == 0) {
            stu32_coh(&cnt[bid], epoch);                  // arrival store
            while (ldu32_coh(&cnt[FLG + bid * 32]) < epoch)
                __builtin_amdgcn_s_sleep(2);              // single reader/line
        }
        __syncthreads();
    }
}

// ---------------- persistent decode loop: phases A (attn), B (LSTM), C (Wu/gate)
// NBLK=256 (1 block/CU). Cross-phase data t-indexed; producers sc1, consumers
// plain cached. A: 8 blocks per batch b (XCD b%8), 256 ctx cols each.
__global__ __launch_bounds__(256, 2) void k_loop(
    const u16* __restrict__ img_bf,
    const u16* __restrict__ Ws_bf,
    float* __restrict__ Wu_all, float* __restrict__ gate_all,
    const float* __restrict__ W_v, const float* __restrict__ b_v,
    u16* __restrict__ xctx_all,
    const u16* __restrict__ emb_all,
    u16* __restrict__ h_all,
    const u16* __restrict__ Wih_bf, const float* __restrict__ b_ih,
    const u16* __restrict__ Whh_bf, const float* __restrict__ b_hh,
    float* __restrict__ c_ws,
    const u16* __restrict__ WU_bf, const float* __restrict__ b_U,
    const u16* __restrict__ Wfb_bf, const float* __restrict__ b_fb,
    unsigned* cnt)
{
    __shared__ float redC[4][2][64][9];   // phase C reduction (pad 8->9)
    __shared__ float redB[4][64][17];     // phase B reduction (pad 16->17)
    __shared__ float wu_sh[HH];           // phase A Wu stage
    __shared__ float part[2][128][3];     // phase A ctx partials (pad 2->3)
    __shared__ float e_sh[NN];            // phase A scores
    __shared__ float a_sh[NN];            // phase A softmax

    const int bid = blockIdx.x, tid = threadIdx.x;
    const int w = tid >> 6, lane = tid & 63, quad = lane >> 4, l16 = lane & 15;
    unsigned snc = 0;

    // ---- phase C: Wu_all[t] = h@W_U.T + b_U ; gate_all[t] = sigm(h@W_fb.T+b) -
    auto phaseC = [&](int tIn) {
        if (bid < 80) {
            int ot = bid;
            const u16* wrow[2];
            #pragma unroll
            for (int s = 0; s < 2; ++s) {
                int o = ot * 32 + s * 16 + l16;
                wrow[s] = (o < HH) ? (WU_bf + (size_t)o * HH)
                                   : (Wfb_bf + (size_t)(o - HH) * HH);
            }
            const u16* hbase = h_all + (size_t)tIn * BB * HH;
            f32x4 acc[2][2];
            for (int mt = 0; mt < 2; ++mt) for (int s = 0; s < 2; ++s) acc[mt][s] = {0,0,0,0};
            for (int c = w * 4; c < w * 4 + 4; ++c) {
                int k = c * 32 + quad * 8;
                bh8 b8[2];
                #pragma unroll
                for (int s = 0; s < 2; ++s) b8[s] = ld8(wrow[s] + k);
                #pragma unroll
                for (int mt = 0; mt < 2; ++mt) {
                    bh8 a8 = ld8(hbase + (size_t)(mt * 16 + l16) * HH + k);   // cached
                    #pragma unroll
                    for (int s = 0; s < 2; ++s)
                        acc[mt][s] = __builtin_amdgcn_mfma_f32_16x16x32_bf16(a8, b8[s], acc[mt][s], 0, 0, 0);
                }
            }
            for (int mt = 0; mt < 2; ++mt)
                for (int s = 0; s < 2; ++s)
                    for (int r = 0; r < 4; ++r) redC[w][mt][lane][s * 4 + r] = acc[mt][s][r];
            __syncthreads();
            for (int idx = tid; idx < 1024; idx += 256) {
                int b = idx & 31, col = idx >> 5;         // col 0..31
                int s = col >> 4, nn = col & 15;
                int mt = b >> 4, m = b & 15;
                int sl = (m >> 2) * 16 + nn, rg = s * 4 + (m & 3);
                float v = redC[0][mt][sl][rg] + redC[1][mt][sl][rg]
                        + redC[2][mt][sl][rg] + redC[3][mt][sl][rg];
                int o = ot * 32 + col;
                if (o < HH)
                    stf_coh(&Wu_all[((size_t)tIn * BB + b) * HH + o], v + b_U[o]);
                else
                    stf_coh(&gate_all[((size_t)tIn * BB + b) * EE + (o - HH)], sigm(v + b_fb[o - HH]));
            }
        }
    };

    // ---- phase A: e = Wv.tanh(Ws+Wu)+bv ; softmax ; xctx = gate*ctx ----------
    // 256 blocks: b = bid&31 (8 blocks of b on XCD b%8), s8 = bid>>5 -> 256 cols.
    auto phaseA = [&](int t) {
        int b = bid & 31, s8 = bid >> 5;
        const float* wubase = Wu_all + ((size_t)t * BB + b) * HH;
        {   // stage Wu[t][b] into LDS (cached; 1 L2 fill + sibling hits per XCD)
            float2 t2 = *reinterpret_cast<const float2*>(wubase + tid * 2);
            wu_sh[tid * 2] = t2.x; wu_sh[tid * 2 + 1] = t2.y;
        }
        __syncthreads();
        float wu[8], wv[8];
        #pragma unroll
        for (int j = 0; j < 8; ++j) { wu[j] = wu_sh[lane * 8 + j]; wv[j] = W_v[lane * 8 + j]; }
        for (int n = w; n < NN; n += 4) {
            bh8 ws8 = ld8(Ws_bf + (size_t)(b * NN + n) * HH + lane * 8);
            float acc = 0.f;
            #pragma unroll
            for (int j = 0; j < 8; ++j) acc += wv[j] * tanh_(bsf((u16)ws8[j]) + wu[j]);
            #pragma unroll
            for (int off = 32; off > 0; off >>= 1) acc += __shfl_down(acc, off, 64);
            if (lane == 0) e_sh[n] = acc + b_v[0];
        }
        __syncthreads();
        if (tid < 64) {
            float e0 = e_sh[tid];
            float e1 = (tid + 64 < NN) ? e_sh[tid + 64] : -1e30f;
            float m = fmaxf(e0, e1);
            #pragma unroll
            for (int off = 32; off > 0; off >>= 1) m = fmaxf(m, __shfl_xor(m, off, 64));
            const float L2E = 1.4426950408889634f;
            float x0 = exp2f((e0 - m) * L2E);
            float x1 = (tid + 64 < NN) ? exp2f((e1 - m) * L2E) : 0.f;
            float s = x0 + x1;
            #pragma unroll
            for (int off = 32; off > 0; off >>= 1) s += __shfl_xor(s, off, 64);
            float inv = __builtin_amdgcn_rcpf(s);
            a_sh[tid] = x0 * inv;
            if (tid + 64 < NN) a_sh[tid + 64] = x1 * inv;
        }
        __syncthreads();
        // ctx over 256 cols (s8 tile): 128 col-pairs x 2-way n-split (49+49)
        int pc = tid & 127, nq = tid >> 7;
        int c0 = s8 * 256 + pc * 2;
        int n0 = nq * 49, n1 = n0 + 49;
        float a0 = 0.f, a1 = 0.f;
        for (int n = n0; n < n1; ++n) {
            unsigned u = *reinterpret_cast<const unsigned*>(img_bf + (size_t)(b * NN + n) * EE + c0);
            float a = a_sh[n];
            a0 = fmaf(a, bsf(u & 0xffffu), a0);
            a1 = fmaf(a, bsf(u >> 16), a1);
        }
        part[nq][pc][0] = a0; part[nq][pc][1] = a1;
        __syncthreads();
        if (tid < 128) {
            float C0 = part[0][tid][0] + part[1][tid][0];
            float C1 = part[0][tid][1] + part[1][tid][1];
            int ec = s8 * 256 + tid * 2;
            float2 g = *reinterpret_cast<const float2*>(
                gate_all + ((size_t)t * BB + b) * EE + ec);               // cached
            unsigned outw = ((unsigned)f2bu(g.y * C1) << 16) | (unsigned)f2bu(g.x * C0);
            stu32_coh(reinterpret_cast<unsigned*>(
                xctx_all + ((size_t)t * BB + b) * EE + ec), outw);        // sc1
        }
    };

    // ---- phase B: gates GEMM (K=3072 concat) + LSTM update -------------------
    auto phaseB = [&](int t) {
        if (bid < 64) {
            int kt = bid & 31, mt = bid >> 5;
            int brow = mt * 16 + l16;
            const u16* embrow = emb_all + (size_t)(t * BB + brow) * HH;
            const u16* xrow   = xctx_all + ((size_t)t * BB + brow) * EE;
            const u16* hrow   = h_all + (size_t)(t * BB + brow) * HH;
            const u16* wihp[4]; const u16* whhp[4];
            #pragma unroll
            for (int jt = 0; jt < 4; ++jt) {
                int j = kt * 16 + jt * 4 + (l16 & 3) + HH * (l16 >> 2);
                wihp[jt] = Wih_bf + (size_t)j * (HH + EE);
                whhp[jt] = Whh_bf + (size_t)j * HH;
            }
            f32x4 acc[4];
            #pragma unroll
            for (int jt = 0; jt < 4; ++jt) acc[jt] = {0,0,0,0};
            for (int c = w * 24; c < w * 24 + 24; ++c) {   // 96 K-chunks of 32
                int k = c * 32 + quad * 8;
                bh8 a8;
                if (c < 16)      a8 = ld8(embrow + k);
                else if (c < 80) a8 = ld8(xrow + (k - HH));          // cached
                else             a8 = ld8(hrow + (k - HH - EE));     // cached
                #pragma unroll
                for (int jt = 0; jt < 4; ++jt) {
                    bh8 b8 = (c < 80) ? ld8(wihp[jt] + k) : ld8(whhp[jt] + (k - HH - EE));
                    acc[jt] = __builtin_amdgcn_mfma_f32_16x16x32_bf16(a8, b8, acc[jt], 0, 0, 0);
                }
            }
            for (int jt = 0; jt < 4; ++jt)
                for (int r = 0; r < 4; ++r) redB[w][lane][jt * 4 + r] = acc[jt][r];
            __syncthreads();
            {   // one LSTM cell per thread: (m, kk) of this block's 16x16 tile
                int m = tid >> 4, kk = tid & 15;
                float g4[4];
                #pragma unroll
                for (int g = 0; g < 4; ++g) {
                    int nn = (kk & 3) | (g << 2);
                    int jt = kk >> 2;
                    int sl = (m >> 2) * 16 + nn, rg = m & 3;
                    int jj = kt * 16 + kk + HH * g;
                    g4[g] = redB[0][sl][jt * 4 + rg] + redB[1][sl][jt * 4 + rg]
                          + redB[2][sl][jt * 4 + rg] + redB[3][sl][jt * 4 + rg]
                          + b_ih[jj] + b_hh[jj];
                }
                int b = mt * 16 + m, k = kt * 16 + kk;
                float cold = c_ws[b * HH + k];
                float c2 = sigm(g4[1]) * cold + sigm(g4[0]) * tanh_(g4[2]);
                float h2 = sigm(g4[3]) * tanh_(c2);
                c_ws[b * HH + k] = c2;
                stu16_coh(&h_all[(size_t)((t + 1) * BB + b) * HH + k], f2bu(h2));  // sc1
            }
        }
    };

    // ---- sequence ------------------------------------------------------------
    phaseC(0);
    gsync(cnt, ++snc);
    for (int t = 0; t < TT; ++t) {
        phaseA(t);
        gsync(cnt, ++snc);
        phaseB(t);
        gsync(cnt, ++snc);
        if (t < TT - 1) {
            phaseC(t + 1);
            gsync(cnt, ++snc);
        }
    }
}

// ---------------- k_pred: all-step pred = h2 @ W_out.T + b_out (MFMA) ---------
__global__ __launch_bounds__(256) void k_pred(
    const u16* __restrict__ h_all, const u16* __restrict__ Wout_bf,
    const float* __restrict__ b_out, float* __restrict__ out)
{
    int bid = blockIdx.x, tid = threadIdx.x;       // 15 mt(128 rows) x 79 vt(128 v)
    int mt = bid / 79, vt = bid % 79;
    int w = tid >> 6, lane = tid & 63, quad = lane >> 4, l16 = lane & 15;
    f32x4 acc[8][2];
    for (int mi = 0; mi < 8; ++mi) for (int s = 0; s < 2; ++s) acc[mi][s] = {0,0,0,0};
    int nact[2]; int vbase[2];
    for (int s = 0; s < 2; ++s) {
        int ntg = vt * 8 + 2 * w + s;               // 625 total 16-wide v-tiles
        nact[s] = (ntg < 625);
        vbase[s] = ntg * 16;
    }
    for (int c = 0; c < 16; ++c) {
        int k = c * 32 + quad * 8;
        bh8 b8[2];
        for (int s = 0; s < 2; ++s) if (nact[s])
            b8[s] = ld8(Wout_bf + (size_t)(vbase[s] + l16) * HH + k);
        for (int mi = 0; mi < 8; ++mi) {
            int row = 32 + mt * 128 + mi * 16 + l16;   // h2 rows (skip h0 block)
            bh8 a8 = ld8(h_all + (size_t)row * HH + k);
            for (int s = 0; s < 2; ++s) if (nact[s])
                acc[mi][s] = __builtin_amdgcn_mfma_f32_16x16x32_bf16(a8, b8[s], acc[mi][s], 0, 0, 0);
        }
    }
    for (int s = 0; s < 2; ++s) if (nact[s]) {
        int v = vbase[s] + l16;
        float bo = b_out[v];
        for (int mi = 0; mi < 8; ++mi)
            for (int r = 0; r < 4; ++r) {
                int row = 32 + mt * 128 + mi * 16 + quad * 4 + r;
                int tt = (row >> 5) - 1, b = row & 31;
                out[(size_t)(b * TT + tt) * VV + v] = acc[mi][s][r] + bo;
            }
    }
}

extern "C" void kernel_launch(void* const* d_in, const int* in_sizes, int n_in,
                              void* d_out, int out_size, void* d_ws, size_t ws_size,
                              hipStream_t stream)
{
    const float* img      = (const float*)d_in[0];
    const int*   caps     = (const int*)d_in[1];
    const float* emb      = (const float*)d_in[2];
    const float* W_init_h = (const float*)d_in[3];
    const float* b_init_h = (const float*)d_in[4];
    const float* W_init_c = (const float*)d_in[5];
    const float* b_init_c = (const float*)d_in[6];
    const float* W_U      = (const float*)d_in[7];
    const float* b_U      = (const float*)d_in[8];
    const float* W_att    = (const float*)d_in[9];
    const float* b_att    = (const float*)d_in[10];
    const float* W_v      = (const float*)d_in[11];
    const float* b_v      = (const float*)d_in[12];
    const float* W_fb     = (const float*)d_in[13];
    const float* b_fb     = (const float*)d_in[14];
    const float* W_ih     = (const float*)d_in[15];
    const float* b_ih     = (const float*)d_in[16];
    const float* W_hh     = (const float*)d_in[17];
    const float* b_hh     = (const float*)d_in[18];
    const float* W_out    = (const float*)d_in[19];
    const float* b_out    = (const float*)d_in[20];
    float* out = (float*)d_out;

    char* ws = (char*)d_ws;
    u16*   img_bf   = (u16*)(ws);                    // 12,845,056 B
    u16*   Watt_bf  = (u16*)(ws + 12845056);         //  2,097,152 B
    u16*   Winh_bf  = (u16*)(ws + 14942208);         //  2,097,152 B
    u16*   Winc_bf  = (u16*)(ws + 17039360);         //  2,097,152 B
    u16*   WU_bf    = (u16*)(ws + 19136512);         //    524,288 B
    u16*   Wfb_bf   = (u16*)(ws + 19660800);         //  2,097,152 B
    u16*   Wih_bf   = (u16*)(ws + 21757952);         // 10,485,760 B
    u16*   Whh_bf   = (u16*)(ws + 32243712);         //  2,097,152 B
    u16*   Wout_bf  = (u16*)(ws + 34340864);         // 10,240,000 B
    u16*   Ws_bf    = (u16*)(ws + 44580864);         //  3,211,264 B
    u16*   emb_all  = (u16*)(ws + 47792128);         //  1,966,080 B
    u16*   h_all    = (u16*)(ws + 49758208);         //  1,998,848 B (61x32x512 u16)
    u16*   avg_bf   = (u16*)(ws + 51757056);         //    131,072 B (dead after init2 -> sync)
    float* c_ws     = (float*)(ws + 51888128);       //     65,536 B
    u16*   xctx_all = (u16*)(ws + 51953664);         //  7,995,392 B (61x32x2048 u16)
    float* Wu_all   = (float*)(ws + 59949056);       //  3,997,696 B (61x32x512 f32)
    float* gate_all = (float*)(ws + 63946752);       // 15,990,784 B (61x32x2048 f32)
    unsigned* sync_cnt = (unsigned*)avg_bf;          // 36 KB inside dead avg_bf region
    // total ws usage: 79,937,536 bytes

    // all fp32 -> bf16 conversions in one launch (dst contiguous at ws base)
    k_conv_all<<<21768, 256, 0, stream>>>(img, W_att, W_init_h, W_init_c, W_U,
                                          W_fb, W_ih, W_hh, W_out, img_bf);

    k_init1<<<496, 256, 0, stream>>>(img, caps, emb, avg_bf, emb_all);
    k_init2<<<64, 256, 0, stream>>>(avg_bf, Winh_bf, b_init_h, Winc_bf, b_init_c, h_all, c_ws);
    k_ws<<<784, 256, 0, stream>>>(img_bf, Watt_bf, b_att, Ws_bf);

    k_zero<<<1, 256, 0, stream>>>(sync_cnt);        // avg_bf is dead from here on
    k_loop<<<NBLK, 256, 0, stream>>>(img_bf, Ws_bf, Wu_all, gate_all, W_v, b_v, xctx_all,
                                     emb_all, h_all, Wih_bf, b_ih, Whh_bf, b_hh, c_ws,
                                     WU_bf, b_U, Wfb_bf, b_fb, sync_cnt);

    k_pred<<<1185, 256, 0, stream>>>(h_all, Wout_bf, b_out, out);
}